// Round 5
// baseline (761.943 us; speedup 1.0000x reference)
//
#include <hip/hip_runtime.h>

static constexpr int KC   = 9;    // kernel bins
static constexpr int CIN  = 32;   // input channels
static constexpr int CA   = 24;   // branch-a out channels
static constexpr int CB   = 8;    // branch-b out channels
static constexpr int COUT = 32;   // CA + CB
static constexpr int WPB  = 12;   // waves (output points) per block
static constexpr int TPB  = WPB * 64;        // 768 threads
static constexpr int WSTR = KC * CIN + 4;    // 292 dwords: W row stride (bank stagger)

// ---------------------------------------------------------------------------
// Kernel 1: CSR row pointer from sorted neighbors_out_index.
// ---------------------------------------------------------------------------
__global__ void build_rowptr(const int* __restrict__ oidx, int* __restrict__ rp,
                             int E, int nout) {
    int e = blockIdx.x * blockDim.x + threadIdx.x;
    if (e >= E) return;
    int cur  = oidx[e];
    int prev = (e == 0) ? -1 : oidx[e - 1];
    for (int id = prev + 1; id <= cur; ++id) rp[id] = e;
    if (e == E - 1) {
        for (int id = cur + 1; id <= nout; ++id) rp[id] = E;
    }
}

// ---------------------------------------------------------------------------
// Kernel 2: pack W_a [9][32][24], W_b [9][32][8] into Wt[f][k][c] with row
// stride WSTR dwords (f-major) for the per-feature epilogue.
// ---------------------------------------------------------------------------
__global__ void pack_weights(const float* __restrict__ Wa,
                             const float* __restrict__ Wb,
                             float* __restrict__ Wt) {
    int t = blockIdx.x * blockDim.x + threadIdx.x;
    if (t >= COUT * KC * CIN) return;
    int f = t / (KC * CIN);
    int r = t % (KC * CIN);            // k*32 + c
    float v = (f < CA) ? Wa[r * CA + f] : Wb[r * CB + (f - CA)];
    Wt[f * WSTR + r] = v;
}

// ---------------------------------------------------------------------------
// Kernel 3: fused edge accumulation + per-feature dot-product epilogue.
// One wave per output point, 12 waves / 768-thread block, 2 blocks/CU.
// Edge loop is WAVE-UNIFORM (tb < cnt with uniform cnt) so every __shfl
// executes with all 64 lanes active (ds_bpermute from masked lanes is
// undefined -- that was round 3's bug).
// ---------------------------------------------------------------------------
__global__ __launch_bounds__(TPB, 6) void fused_conv(
    const float* __restrict__ feats, const float* __restrict__ importance,
    const float* __restrict__ Wt, const float* __restrict__ ba,
    const float* __restrict__ bb,
    const int* __restrict__ nidx, const int* __restrict__ nkidx,
    const int* __restrict__ rp,
    float* __restrict__ outf, float* __restrict__ outimp, int nout)
{
    __shared__ __align__(16) float sW[COUT * WSTR];        // 37376 B
    __shared__ __align__(16) float sS[WPB][2][KC * CIN];   // 27648 B

    const int wave = threadIdx.x >> 6;
    const int lane = threadIdx.x & 63;
    const int c    = lane & 31;
    const int h    = lane >> 5;
    const int n    = blockIdx.x * WPB + wave;

    // stage weights (coalesced float4) + zero S tiles
    {
        const float4* src = reinterpret_cast<const float4*>(Wt);
        float4*       dst = reinterpret_cast<float4*>(sW);
        for (int i = threadIdx.x; i < COUT * WSTR / 4; i += TPB) dst[i] = src[i];
        float* pS = &sS[0][0][0];
        for (int i = threadIdx.x; i < WPB * 2 * KC * CIN; i += TPB) pS[i] = 0.f;
    }
    __syncthreads();

    int start = 0, end = 0;
    if (n < nout) { start = rp[n]; end = rp[n + 1]; }

    float* mySA = &sS[wave][0][0];
    float* mySB = &sS[wave][1][0];

    float accImp = 0.f;
    for (int base = start; base < end; base += 64) {
        int cnt = end - base; if (cnt > 64) cnt = 64;   // wave-uniform

        // metadata in registers: lane j <-> edge base+j (zeros beyond cnt)
        int idxv = 0, kkv = 0; float impv = 0.f;
        if (lane < cnt) {
            int j = base + lane;
            idxv = nidx[j];
            kkv  = nkidx[j];
            impv = importance[idxv];
        }
        accImp += impv;

        // UNIFORM loop: both halves run identical iterations; per-edge masks.
        // Sources tb+h+{0,2,4,6} <= tb+7 <= 63: never wrap, always active.
        for (int tb = 0; tb < cnt; tb += 8) {
            int   t  = tb + h;
            int   i0 = __shfl(idxv, t, 64),     i1 = __shfl(idxv, t + 2, 64);
            int   i2 = __shfl(idxv, t + 4, 64), i3 = __shfl(idxv, t + 6, 64);
            int   k0 = __shfl(kkv,  t, 64),     k1 = __shfl(kkv,  t + 2, 64);
            int   k2 = __shfl(kkv,  t + 4, 64), k3 = __shfl(kkv,  t + 6, 64);
            float m0 = __shfl(impv, t, 64),     m1 = __shfl(impv, t + 2, 64);
            float m2 = __shfl(impv, t + 4, 64), m3 = __shfl(impv, t + 6, 64);
            // 4 independent coalesced row gathers in flight
            float f0 = feats[(size_t)i0 * CIN + c];
            float f1 = feats[(size_t)i1 * CIN + c];
            float f2 = feats[(size_t)i2 * CIN + c];
            float f3 = feats[(size_t)i3 * CIN + c];
            // mask out-of-range edges (zero f and m kills both adds)
            if (t     >= cnt) { f0 = 0.f; m0 = 0.f; }
            if (t + 2 >= cnt) { f1 = 0.f; m1 = 0.f; }
            if (t + 4 >= cnt) { f2 = 0.f; m2 = 0.f; }
            if (t + 6 >= cnt) { f3 = 0.f; m3 = 0.f; }
            atomicAdd(&mySA[k0 * CIN + c], f0);
            atomicAdd(&mySB[k0 * CIN + c], f0 * m0);
            atomicAdd(&mySA[k1 * CIN + c], f1);
            atomicAdd(&mySB[k1 * CIN + c], f1 * m1);
            atomicAdd(&mySA[k2 * CIN + c], f2);
            atomicAdd(&mySB[k2 * CIN + c], f2 * m2);
            atomicAdd(&mySA[k3 * CIN + c], f3);
            atomicAdd(&mySB[k3 * CIN + c], f3 * m3);
        }
    }
    if (n >= nout) return;

    // importance total (disjoint per-lane partials -> full 64-lane reduce)
    float impTot = accImp;
#pragma unroll
    for (int m = 1; m < 64; m <<= 1) impTot += __shfl_xor(impTot, m, 64);
    float denom = impTot > 0.f ? impTot : 1.f;

    // per-feature dot product: lane (h, f=c) accumulates its half's channels
    // S reads are broadcast (uniform per half); W reads are strided b128.
    const int f = c;
    const float* Sbase = (f < CA) ? mySA : mySB;
    const float* Wbase = sW + f * WSTR;
    float acc0 = 0.f, acc1 = 0.f, acc2 = 0.f, acc3 = 0.f;
#pragma unroll
    for (int k = 0; k < KC; ++k) {
        int off = k * CIN + h * 16;
        float4 s0 = *reinterpret_cast<const float4*>(Sbase + off);
        float4 s1 = *reinterpret_cast<const float4*>(Sbase + off + 4);
        float4 s2 = *reinterpret_cast<const float4*>(Sbase + off + 8);
        float4 s3 = *reinterpret_cast<const float4*>(Sbase + off + 12);
        float4 w0 = *reinterpret_cast<const float4*>(Wbase + off);
        float4 w1 = *reinterpret_cast<const float4*>(Wbase + off + 4);
        float4 w2 = *reinterpret_cast<const float4*>(Wbase + off + 8);
        float4 w3 = *reinterpret_cast<const float4*>(Wbase + off + 12);
        acc0 = fmaf(s0.x, w0.x, fmaf(s0.y, w0.y, fmaf(s0.z, w0.z, fmaf(s0.w, w0.w, acc0))));
        acc1 = fmaf(s1.x, w1.x, fmaf(s1.y, w1.y, fmaf(s1.z, w1.z, fmaf(s1.w, w1.w, acc1))));
        acc2 = fmaf(s2.x, w2.x, fmaf(s2.y, w2.y, fmaf(s2.z, w2.z, fmaf(s2.w, w2.w, acc2))));
        acc3 = fmaf(s3.x, w3.x, fmaf(s3.y, w3.y, fmaf(s3.z, w3.z, fmaf(s3.w, w3.w, acc3))));
    }
    float acc = (acc0 + acc1) + (acc2 + acc3);
    float tot = acc + __shfl_xor(acc, 32, 64);   // combine the two halves

    if (h == 0) {
        float res = (f < CA) ? (tot + ba[f]) : (tot / denom + bb[f - CA]);
        outf[(size_t)n * COUT + f] = fmaxf(res, 0.f);
    }
    if (lane == 0) outimp[n] = impTot;
}

// ---------------------------------------------------------------------------
extern "C" void kernel_launch(void* const* d_in, const int* in_sizes, int n_in,
                              void* d_out, int out_size, void* d_ws, size_t ws_size,
                              hipStream_t stream) {
    const float* feats      = (const float*)d_in[0];
    const float* importance = (const float*)d_in[1];
    const float* Wa         = (const float*)d_in[2];
    const float* ba         = (const float*)d_in[3];
    const float* Wb         = (const float*)d_in[4];
    const float* bb         = (const float*)d_in[5];
    const int*   nidx       = (const int*)d_in[6];
    const int*   nkidx      = (const int*)d_in[7];
    const int*   noidx      = (const int*)d_in[8];

    const int E    = in_sizes[6];
    const int nout = out_size / (COUT + 1);

    float* outf   = (float*)d_out;
    float* outimp = outf + (size_t)nout * COUT;

    int*   rp = (int*)d_ws;
    size_t rp_bytes = ((size_t)(nout + 1) * sizeof(int) + 255) & ~(size_t)255;
    float* Wt = (float*)((char*)d_ws + rp_bytes);   // COUT*WSTR dwords

    build_rowptr<<<(E + 255) / 256, 256, 0, stream>>>(noidx, rp, E, nout);
    pack_weights<<<(COUT * KC * CIN + 255) / 256, 256, 0, stream>>>(Wa, Wb, Wt);
    fused_conv<<<(nout + WPB - 1) / WPB, TPB, 0, stream>>>(
        feats, importance, Wt, ba, bb, nidx, nkidx, rp, outf, outimp, nout);
}

// Round 6
// 596.351 us; speedup vs baseline: 1.2777x; 1.2777x over previous
//
#include <hip/hip_runtime.h>

static constexpr int KC   = 9;    // kernel bins
static constexpr int CIN  = 32;   // input channels
static constexpr int CA   = 24;   // branch-a out channels
static constexpr int CB   = 8;    // branch-b out channels
static constexpr int COUT = 32;   // CA + CB
static constexpr int WSTR = KC * CIN + 4;    // 292 dwords: W row stride (16B-aligned)

// ---------------------------------------------------------------------------
// pack W_a [9][32][24], W_b [9][32][8] into Wt[f][k][c] (row stride WSTR).
// ---------------------------------------------------------------------------
__global__ void pack_weights(const float* __restrict__ Wa,
                             const float* __restrict__ Wb,
                             float* __restrict__ Wt) {
    int t = blockIdx.x * blockDim.x + threadIdx.x;
    if (t >= COUT * KC * CIN) return;
    int f = t / (KC * CIN);
    int r = t % (KC * CIN);            // k*32 + c
    float v = (f < CA) ? Wa[r * CA + f] : Wb[r * CB + (f - CA)];
    Wt[f * WSTR + r] = v;
}

// ---------------------------------------------------------------------------
// Phase A: edge-parallel accumulation. Half-wave (32 lanes = channels) owns a
// contiguous edge chunk; 4-edge unroll for MLP; global f32 atomics into
// Sa/Sb [nout][9][32] and impAcc [nout].
// ---------------------------------------------------------------------------
__global__ __launch_bounds__(256) void edge_accum(
    const float* __restrict__ feats, const float* __restrict__ importance,
    const int* __restrict__ nidx, const int* __restrict__ nkidx,
    const int* __restrict__ noidx,
    float* __restrict__ Sa, float* __restrict__ Sb,
    float* __restrict__ impAcc, int E)
{
    const int t   = blockIdx.x * 256 + threadIdx.x;
    const int c   = t & 31;
    const int hw  = t >> 5;                    // global half-wave id
    const int nhw = (gridDim.x * 256) >> 5;
    int per = (E + nhw - 1) / nhw;
    int e0  = hw * per;
    int e1  = e0 + per; if (e1 > E) e1 = E;
    if (e0 >= E) return;

    int e = e0;
    for (; e + 3 < e1; e += 4) {
        // 12 independent metadata loads (uniform per half -> broadcast)
        int n0 = noidx[e],     n1 = noidx[e + 1];
        int n2 = noidx[e + 2], n3 = noidx[e + 3];
        int i0 = nidx[e],      i1 = nidx[e + 1];
        int i2 = nidx[e + 2],  i3 = nidx[e + 3];
        int q0 = nkidx[e],     q1 = nkidx[e + 1];
        int q2 = nkidx[e + 2], q3 = nkidx[e + 3];
        // 4 independent importance broadcasts + 4 independent row gathers
        float m0 = importance[i0], m1 = importance[i1];
        float m2 = importance[i2], m3 = importance[i3];
        float f0 = feats[(size_t)i0 * CIN + c];
        float f1 = feats[(size_t)i1 * CIN + c];
        float f2 = feats[(size_t)i2 * CIN + c];
        float f3 = feats[(size_t)i3 * CIN + c];
        size_t b0 = ((size_t)n0 * KC + q0) * CIN + c;
        size_t b1 = ((size_t)n1 * KC + q1) * CIN + c;
        size_t b2 = ((size_t)n2 * KC + q2) * CIN + c;
        size_t b3 = ((size_t)n3 * KC + q3) * CIN + c;
        atomicAdd(&Sa[b0], f0);  atomicAdd(&Sb[b0], f0 * m0);
        atomicAdd(&Sa[b1], f1);  atomicAdd(&Sb[b1], f1 * m1);
        atomicAdd(&Sa[b2], f2);  atomicAdd(&Sb[b2], f2 * m2);
        atomicAdd(&Sa[b3], f3);  atomicAdd(&Sb[b3], f3 * m3);
        if (c == 0) {
            atomicAdd(&impAcc[n0], m0);
            atomicAdd(&impAcc[n1], m1);
            atomicAdd(&impAcc[n2], m2);
            atomicAdd(&impAcc[n3], m3);
        }
    }
    for (; e < e1; ++e) {
        int   n0 = noidx[e], i0 = nidx[e], q0 = nkidx[e];
        float m0 = importance[i0];
        float f0 = feats[(size_t)i0 * CIN + c];
        size_t b0 = ((size_t)n0 * KC + q0) * CIN + c;
        atomicAdd(&Sa[b0], f0);
        atomicAdd(&Sb[b0], f0 * m0);
        if (c == 0) atomicAdd(&impAcc[n0], m0);
    }
}

// ---------------------------------------------------------------------------
// Phase B: point-parallel epilogue. One wave per point; lane (h, f=c)
// accumulates its channel-half's dot product from global S + LDS weights,
// one shfl_xor(32) combine.
// ---------------------------------------------------------------------------
__global__ __launch_bounds__(256) void epilogue(
    const float* __restrict__ Sa, const float* __restrict__ Sb,
    const float* __restrict__ impAcc, const float* __restrict__ Wt,
    const float* __restrict__ ba, const float* __restrict__ bb,
    float* __restrict__ outf, float* __restrict__ outimp, int nout)
{
    __shared__ __align__(16) float sW[COUT * WSTR];   // 37376 B
    {
        const float4* src = reinterpret_cast<const float4*>(Wt);
        float4*       dst = reinterpret_cast<float4*>(sW);
        for (int i = threadIdx.x; i < COUT * WSTR / 4; i += 256) dst[i] = src[i];
    }
    __syncthreads();

    const int wave = threadIdx.x >> 6;
    const int lane = threadIdx.x & 63;
    const int c    = lane & 31;
    const int h    = lane >> 5;
    const int n    = blockIdx.x * 4 + wave;
    if (n >= nout) return;

    float impTot = impAcc[n];
    float denom  = impTot > 0.f ? impTot : 1.f;

    const int f = c;
    const float* Sbase = ((f < CA) ? Sa : Sb) + (size_t)n * (KC * CIN);
    const float* Wbase = sW + f * WSTR;
    float acc0 = 0.f, acc1 = 0.f, acc2 = 0.f, acc3 = 0.f;
#pragma unroll
    for (int k = 0; k < KC; ++k) {
        int off = k * CIN + h * 16;
        float4 s0 = *reinterpret_cast<const float4*>(Sbase + off);
        float4 s1 = *reinterpret_cast<const float4*>(Sbase + off + 4);
        float4 s2 = *reinterpret_cast<const float4*>(Sbase + off + 8);
        float4 s3 = *reinterpret_cast<const float4*>(Sbase + off + 12);
        float4 w0 = *reinterpret_cast<const float4*>(Wbase + off);
        float4 w1 = *reinterpret_cast<const float4*>(Wbase + off + 4);
        float4 w2 = *reinterpret_cast<const float4*>(Wbase + off + 8);
        float4 w3 = *reinterpret_cast<const float4*>(Wbase + off + 12);
        acc0 = fmaf(s0.x, w0.x, fmaf(s0.y, w0.y, fmaf(s0.z, w0.z, fmaf(s0.w, w0.w, acc0))));
        acc1 = fmaf(s1.x, w1.x, fmaf(s1.y, w1.y, fmaf(s1.z, w1.z, fmaf(s1.w, w1.w, acc1))));
        acc2 = fmaf(s2.x, w2.x, fmaf(s2.y, w2.y, fmaf(s2.z, w2.z, fmaf(s2.w, w2.w, acc2))));
        acc3 = fmaf(s3.x, w3.x, fmaf(s3.y, w3.y, fmaf(s3.z, w3.z, fmaf(s3.w, w3.w, acc3))));
    }
    float acc = (acc0 + acc1) + (acc2 + acc3);
    float tot = acc + __shfl_xor(acc, 32, 64);

    if (h == 0) {
        float res = (f < CA) ? (tot + ba[f]) : (tot / denom + bb[f - CA]);
        outf[(size_t)n * COUT + f] = fmaxf(res, 0.f);
    }
    if (lane == 0) outimp[n] = impTot;
}

// ===========================================================================
// Fallback path (round-4 fused kernel) for when ws is too small for scratch.
// ===========================================================================
static constexpr int WPB = 12;
static constexpr int TPB = WPB * 64;

__global__ void build_rowptr(const int* __restrict__ oidx, int* __restrict__ rp,
                             int E, int nout) {
    int e = blockIdx.x * blockDim.x + threadIdx.x;
    if (e >= E) return;
    int cur  = oidx[e];
    int prev = (e == 0) ? -1 : oidx[e - 1];
    for (int id = prev + 1; id <= cur; ++id) rp[id] = e;
    if (e == E - 1) {
        for (int id = cur + 1; id <= nout; ++id) rp[id] = E;
    }
}

__global__ __launch_bounds__(TPB, 6) void fused_conv(
    const float* __restrict__ feats, const float* __restrict__ importance,
    const float* __restrict__ Wt, const float* __restrict__ ba,
    const float* __restrict__ bb,
    const int* __restrict__ nidx, const int* __restrict__ nkidx,
    const int* __restrict__ rp,
    float* __restrict__ outf, float* __restrict__ outimp, int nout)
{
    __shared__ __align__(16) float sW[COUT * WSTR];
    __shared__ __align__(16) float sS[WPB][2][KC * CIN];

    const int wave = threadIdx.x >> 6;
    const int lane = threadIdx.x & 63;
    const int c    = lane & 31;
    const int h    = lane >> 5;
    const int n    = blockIdx.x * WPB + wave;

    {
        const float4* src = reinterpret_cast<const float4*>(Wt);
        float4*       dst = reinterpret_cast<float4*>(sW);
        for (int i = threadIdx.x; i < COUT * WSTR / 4; i += TPB) dst[i] = src[i];
        float* pS = &sS[0][0][0];
        for (int i = threadIdx.x; i < WPB * 2 * KC * CIN; i += TPB) pS[i] = 0.f;
    }
    __syncthreads();

    int start = 0, end = 0;
    if (n < nout) { start = rp[n]; end = rp[n + 1]; }

    float* mySA = &sS[wave][0][0];
    float* mySB = &sS[wave][1][0];

    float accImp = 0.f;
    for (int base = start; base < end; base += 64) {
        int cnt = end - base; if (cnt > 64) cnt = 64;
        int idxv = 0, kkv = 0; float impv = 0.f;
        if (lane < cnt) {
            int j = base + lane;
            idxv = nidx[j];
            kkv  = nkidx[j];
            impv = importance[idxv];
        }
        accImp += impv;
        for (int tb = 0; tb < cnt; tb += 8) {
            int   t  = tb + h;
            int   i0 = __shfl(idxv, t, 64),     i1 = __shfl(idxv, t + 2, 64);
            int   i2 = __shfl(idxv, t + 4, 64), i3 = __shfl(idxv, t + 6, 64);
            int   k0 = __shfl(kkv,  t, 64),     k1 = __shfl(kkv,  t + 2, 64);
            int   k2 = __shfl(kkv,  t + 4, 64), k3 = __shfl(kkv,  t + 6, 64);
            float m0 = __shfl(impv, t, 64),     m1 = __shfl(impv, t + 2, 64);
            float m2 = __shfl(impv, t + 4, 64), m3 = __shfl(impv, t + 6, 64);
            float f0 = feats[(size_t)i0 * CIN + c];
            float f1 = feats[(size_t)i1 * CIN + c];
            float f2 = feats[(size_t)i2 * CIN + c];
            float f3 = feats[(size_t)i3 * CIN + c];
            if (t     >= cnt) { f0 = 0.f; m0 = 0.f; }
            if (t + 2 >= cnt) { f1 = 0.f; m1 = 0.f; }
            if (t + 4 >= cnt) { f2 = 0.f; m2 = 0.f; }
            if (t + 6 >= cnt) { f3 = 0.f; m3 = 0.f; }
            atomicAdd(&mySA[k0 * CIN + c], f0);
            atomicAdd(&mySB[k0 * CIN + c], f0 * m0);
            atomicAdd(&mySA[k1 * CIN + c], f1);
            atomicAdd(&mySB[k1 * CIN + c], f1 * m1);
            atomicAdd(&mySA[k2 * CIN + c], f2);
            atomicAdd(&mySB[k2 * CIN + c], f2 * m2);
            atomicAdd(&mySA[k3 * CIN + c], f3);
            atomicAdd(&mySB[k3 * CIN + c], f3 * m3);
        }
    }
    if (n >= nout) return;

    float impTot = accImp;
#pragma unroll
    for (int m = 1; m < 64; m <<= 1) impTot += __shfl_xor(impTot, m, 64);
    float denom = impTot > 0.f ? impTot : 1.f;

    const int f = c;
    const float* Sbase = (f < CA) ? mySA : mySB;
    const float* Wbase = sW + f * WSTR;
    float acc0 = 0.f, acc1 = 0.f, acc2 = 0.f, acc3 = 0.f;
#pragma unroll
    for (int k = 0; k < KC; ++k) {
        int off = k * CIN + h * 16;
        float4 s0 = *reinterpret_cast<const float4*>(Sbase + off);
        float4 s1 = *reinterpret_cast<const float4*>(Sbase + off + 4);
        float4 s2 = *reinterpret_cast<const float4*>(Sbase + off + 8);
        float4 s3 = *reinterpret_cast<const float4*>(Sbase + off + 12);
        float4 w0 = *reinterpret_cast<const float4*>(Wbase + off);
        float4 w1 = *reinterpret_cast<const float4*>(Wbase + off + 4);
        float4 w2 = *reinterpret_cast<const float4*>(Wbase + off + 8);
        float4 w3 = *reinterpret_cast<const float4*>(Wbase + off + 12);
        acc0 = fmaf(s0.x, w0.x, fmaf(s0.y, w0.y, fmaf(s0.z, w0.z, fmaf(s0.w, w0.w, acc0))));
        acc1 = fmaf(s1.x, w1.x, fmaf(s1.y, w1.y, fmaf(s1.z, w1.z, fmaf(s1.w, w1.w, acc1))));
        acc2 = fmaf(s2.x, w2.x, fmaf(s2.y, w2.y, fmaf(s2.z, w2.z, fmaf(s2.w, w2.w, acc2))));
        acc3 = fmaf(s3.x, w3.x, fmaf(s3.y, w3.y, fmaf(s3.z, w3.z, fmaf(s3.w, w3.w, acc3))));
    }
    float acc = (acc0 + acc1) + (acc2 + acc3);
    float tot = acc + __shfl_xor(acc, 32, 64);

    if (h == 0) {
        float res = (f < CA) ? (tot + ba[f]) : (tot / denom + bb[f - CA]);
        outf[(size_t)n * COUT + f] = fmaxf(res, 0.f);
    }
    if (lane == 0) outimp[n] = impTot;
}

// ---------------------------------------------------------------------------
extern "C" void kernel_launch(void* const* d_in, const int* in_sizes, int n_in,
                              void* d_out, int out_size, void* d_ws, size_t ws_size,
                              hipStream_t stream) {
    const float* feats      = (const float*)d_in[0];
    const float* importance = (const float*)d_in[1];
    const float* Wa         = (const float*)d_in[2];
    const float* ba         = (const float*)d_in[3];
    const float* Wb         = (const float*)d_in[4];
    const float* bb         = (const float*)d_in[5];
    const int*   nidx       = (const int*)d_in[6];
    const int*   nkidx      = (const int*)d_in[7];
    const int*   noidx      = (const int*)d_in[8];

    const int E    = in_sizes[6];
    const int nout = out_size / (COUT + 1);

    float* outf   = (float*)d_out;
    float* outimp = outf + (size_t)nout * COUT;

    // scratch layout for the edge-parallel path
    const size_t sa_b    = (size_t)nout * KC * CIN * sizeof(float);
    const size_t off_sb  = (sa_b + 255) & ~(size_t)255;
    const size_t off_imp = (off_sb + sa_b + 255) & ~(size_t)255;
    const size_t off_wt  = (off_imp + (size_t)nout * sizeof(float) + 255) & ~(size_t)255;
    const size_t need    = off_wt + (size_t)COUT * WSTR * sizeof(float);

    if (ws_size >= need) {
        float* Sa     = (float*)d_ws;
        float* Sb     = (float*)((char*)d_ws + off_sb);
        float* impAcc = (float*)((char*)d_ws + off_imp);
        float* Wt     = (float*)((char*)d_ws + off_wt);

        hipMemsetAsync(d_ws, 0, off_wt, stream);   // zero Sa, Sb, impAcc
        pack_weights<<<(COUT * KC * CIN + 255) / 256, 256, 0, stream>>>(Wa, Wb, Wt);
        edge_accum<<<2048, 256, 0, stream>>>(feats, importance, nidx, nkidx,
                                             noidx, Sa, Sb, impAcc, E);
        epilogue<<<(nout + 3) / 4, 256, 0, stream>>>(Sa, Sb, impAcc, Wt, ba, bb,
                                                     outf, outimp, nout);
    } else {
        // fallback: fused wave-per-point (round 4)
        int*   rp = (int*)d_ws;
        size_t rp_bytes = ((size_t)(nout + 1) * sizeof(int) + 255) & ~(size_t)255;
        float* Wt = (float*)((char*)d_ws + rp_bytes);

        build_rowptr<<<(E + 255) / 256, 256, 0, stream>>>(noidx, rp, E, nout);
        pack_weights<<<(COUT * KC * CIN + 255) / 256, 256, 0, stream>>>(Wa, Wb, Wt);
        fused_conv<<<(nout + WPB - 1) / WPB, TPB, 0, stream>>>(
            feats, importance, Wt, ba, bb, nidx, nkidx, rp, outf, outimp, nout);
    }
}